// Round 23
// baseline (60.383 us; speedup 1.0000x reference)
//
#include <hip/hip_runtime.h>
#include <hip/hip_bf16.h>
#include <stdint.h>

typedef _Float16 f16x8 __attribute__((ext_vector_type(8)));
typedef float    f32x4 __attribute__((ext_vector_type(4)));

#define CIN   64
#define COUT  128
#define HH    128
#define WW    128
#define BB    8

#define TROW  130                         // y' rows per batch (halo rows 0,129 zero)
#define ROWBYTES (130 * 128)              // 16640 B per (b,y') row: 130 x' * 64c * 2B
#define TSIZE ((size_t)BB * TROW * ROWBYTES)   // 17,305,600 B

#define AS1 __attribute__((address_space(1)))
#define AS3 __attribute__((address_space(3)))

// T row byte layout (f16, c-innermost, XOR-swizzled 16B slots):
//   byte(x', c) = x'*128 + (((c>>3) ^ (x'&7)) << 4) + (c&7)*2

// ---------------- pass 0: weights -> MFMA-A frag order (f16) + halo-row zeroing --
// frag[((ot*18 + s)*64 + lane)*8 + j] = W2[ot*16+(l&15)][c*9+k],
//   c = (s&1)*32 + ((l>>4)&3)*8 + j; k = s>>1
__global__ void prep_plus(const float* __restrict__ wflat, _Float16* __restrict__ bp,
                          _Float16* __restrict__ T) {
    int gid = blockIdx.x * 256 + threadIdx.x;
    if (gid < 8 * 18 * 64 * 8) {
        int j = gid & 7;
        int l = (gid >> 3) & 63;
        int s = (gid >> 9) % 18;
        int n = gid / (18 * 512);
        int o = n * 16 + (l & 15);
        int c = ((s & 1) << 5) + ((l >> 4) << 3) + j;
        int k = s >> 1;
        bp[gid] = (_Float16)wflat[o * 576 + c * 9 + k];
        return;
    }
    int h = gid - 8 * 18 * 64 * 8;
    if (h < 16 * 1040) {                  // zero halo rows y'=0,129 of each batch
        int row = h / 1040, c = h - row * 1040;
        int b = row >> 1, yp = (row & 1) * 129;
        f16x8 z = {};
        *(f16x8*)((char*)T + (size_t)(b * TROW + yp) * ROWBYTES + c * 16) = z;
    }
}

// ---------------- pass 1: input (B,C,H,W) f32 -> T[b][y'][x'][c] f16, swizzled ---
__global__ __launch_bounds__(256) void transpose_pass(const float* __restrict__ inp,
                                                      _Float16* __restrict__ T) {
    __shared__ float sT[64][129];
    const int b   = blockIdx.x >> 7;
    const int y   = blockIdx.x & 127;
    const int tid = threadIdx.x;

    const float* ib = inp + ((long)b * CIN * HH + y) * WW;
    const int xq = tid & 31, c8 = tid >> 5;
    #pragma unroll
    for (int i = 0; i < 8; ++i) {
        int c = c8 * 8 + i;
        float4 v = *(const float4*)(ib + (long)c * (HH * WW) + (xq << 2));
        *(float4*)&sT[c][xq << 2] = v;
    }
    __syncthreads();

    const int x  = tid & 127;
    const int ch = tid >> 7;
    char* rowp = (char*)T + (size_t)(b * TROW + y + 1) * ROWBYTES + (size_t)(x + 1) * 128;
    const int sw = (x + 1) & 7;
    for (int c0 = ch * 8; c0 < 64; c0 += 16) {
        f16x8 v;
        #pragma unroll
        for (int j = 0; j < 8; ++j) v[j] = (_Float16)sT[c0 + j][x];
        *(f16x8*)(rowp + (((c0 >> 3) ^ sw) << 4)) = v;
    }
    if (tid < 16) {   // zero col halos x'=0, x'=129
        char* basep = (char*)T + (size_t)(b * TROW + y + 1) * ROWBYTES
                    + ((tid >> 3) ? 129 * 128 : 0) + (tid & 7) * 16;
        f16x8 z = {};
        *(f16x8*)basep = z;
    }
}

// ---- pass 2: main — block = (b, 2-row strip), FULL 128 px x 128 o ---------------
// 256 thr = 4 waves = 4 px-quarters; EACH wave computes ALL 128 o for its 32 px
// x 2 rows. Per K-step: 4 ds_read_b128 -> 32 MFMAs (read:MFMA = 0.125). Weights
// streamed once per wave (147KB, L2-hot) via 2-deep double buffer af[2][8].
// acc[2][2][8] in AGPRs. One barrier; K-loop barrier-free, base+imm addressing.
// R23: setprio removed (T5 is null-to-negative on non-phase-split GEMMs, m190).
__global__ __launch_bounds__(256, 2) void depthcnn_main(
    const _Float16* __restrict__ T, const float* __restrict__ gbuf,
    const float* __restrict__ bias, const _Float16* __restrict__ aprep,
    float* __restrict__ out)
{
    __shared__ __align__(1024) char sIn[4 * ROWBYTES];   // 66,560 B: 4 full T rows
    __shared__ _Float16 sWf[2][9][128];                  // 4,608 B -> 71,168 total

    const int blk    = blockIdx.x;
    const int b      = blk & 7;            // XCD-pinned: batch b -> XCD b
    const int strip  = blk >> 3;           // 2-row strip (0..63)
    const int ystart = strip << 1;

    const int tid  = threadIdx.x;
    const int wave = tid >> 6;             // px quarter 0..3
    const int lane = tid & 63;
    const int l15  = lane & 15;
    const int g4   = lane >> 4;
    const int x0w  = wave << 5;            // wave's 32-px base

    // ---- stage 4 full T rows (ystart..ystart+3) via async DMA (4160 chunks)
    {
        const char* Tb = (const char*)T + ((size_t)b * TROW + ystart) * ROWBYTES;
        #pragma unroll
        for (int tt = 0; tt < 17; ++tt) {
            int t = tt * 256 + tid;
            if (t < 4 * 1040) {
                int tr = t / 1040, c = t - tr * 1040;
                __builtin_amdgcn_global_load_lds(
                    (const AS1 uint32_t*)(Tb + (size_t)tr * ROWBYTES + c * 16),
                    (AS3 uint32_t*)(sIn + tr * ROWBYTES + c * 16), 16, 0, 0);
            }
        }
    }

    // ---- weight tap-0 frags for all 8 o-tiles, issued before the barrier
    const char* ap = (const char*)aprep + lane * 16;     // + (ot*18 + s)*1024
    f16x8 af[2][8];
    #pragma unroll
    for (int ot = 0; ot < 8; ++ot)
        af[0][ot] = *(const f16x8*)(ap + (size_t)(ot * 18) * 1024);

    // ---- wf: one (row, px) item per thread — fully parallel
    {
        const int r = tid >> 7, px = tid & 127, y = ystart + r;
        const float* g = gbuf + ((size_t)b * 2 + 1) * (HH * WW);
        float dc = 2.f * (g[y * WW + px] - 0.5f);
        float e[9];
        float ssum = 0.f;
        #pragma unroll
        for (int k = 0; k < 9; ++k) {
            int yy = y + (k / 3) - 1;
            int xx = px + (k % 3) - 1;
            float dn = 0.f;
            if ((unsigned)yy < 128u && (unsigned)xx < 128u)
                dn = 2.f * (g[yy * WW + xx] - 0.5f);
            float df = dn - dc;
            float ek = __expf(-df * df);
            e[k] = ek;
            ssum += ek;
        }
        float sc = 9.f / ssum;
        #pragma unroll
        for (int k = 0; k < 9; ++k) sWf[r][k][px] = (_Float16)(e[k] * sc);
    }

    __syncthreads();   // ONE barrier: DMA stage + wf visible. K-loop barrier-free.

    // ---- precomputed swizzled LDS bases: 6 input (dx,ch) + 1 wf
    const char* binA[3][2];
    #pragma unroll
    for (int d = 0; d < 3; ++d)
        #pragma unroll
        for (int ch = 0; ch < 2; ++ch)
            binA[d][ch] = sIn + (x0w << 7) + (((l15 + d) << 7)
                        + ((((ch << 2) | g4) ^ ((l15 + d) & 7)) << 4));
    const char* bwf = (const char*)&sWf[0][0][0] + ((x0w + l15) << 1);
    // imm: (r*9+k)*256 + pt*32

    f32x4 acc[2][2][8];   // [row][pt][ot] — 128 AGPRs
    #pragma unroll
    for (int r = 0; r < 2; ++r)
        #pragma unroll
        for (int pt = 0; pt < 2; ++pt)
            #pragma unroll
            for (int ot = 0; ot < 8; ++ot)
                acc[r][pt][ot] = (f32x4){0.f, 0.f, 0.f, 0.f};

    #pragma unroll
    for (int s = 0; s < 18; ++s) {
        if (s < 17) {   // prefetch next K-step's 8 weight frags (L2-hot, 8KB/wave)
            #pragma unroll
            for (int ot = 0; ot < 8; ++ot)
                af[(s + 1) & 1][ot] = *(const f16x8*)(ap + (size_t)(ot * 18 + s + 1) * 1024);
        }
        const int tap = s >> 1;
        const int ch  = s & 1;
        const int dy  = tap / 3;
        const int dx  = tap - 3 * dy;
        #pragma unroll
        for (int r = 0; r < 2; ++r) {
            _Float16 wh[2];
            #pragma unroll
            for (int pt = 0; pt < 2; ++pt)
                wh[pt] = *(const _Float16*)(bwf + ((r * 9 + tap) * 256 + pt * 32));
            f16x8 bf[2];
            #pragma unroll
            for (int pt = 0; pt < 2; ++pt) {
                f16x8 iv = *(const f16x8*)(binA[dx][ch]
                         + ((r + dy) * ROWBYTES + (pt << 11)));
                f16x8 w8 = {wh[pt], wh[pt], wh[pt], wh[pt],
                            wh[pt], wh[pt], wh[pt], wh[pt]};
                bf[pt] = iv * w8;
            }
            #pragma unroll
            for (int ot = 0; ot < 8; ++ot) {
                acc[r][0][ot] = __builtin_amdgcn_mfma_f32_16x16x32_f16(
                    af[s & 1][ot], bf[0], acc[r][0][ot], 0, 0, 0);
                acc[r][1][ot] = __builtin_amdgcn_mfma_f32_16x16x32_f16(
                    af[s & 1][ot], bf[1], acc[r][1][ot], 0, 0, 0);
            }
        }
    }

    // ---- epilogue: D row = o (g4*4+r4 within tile), col = px (l15) -> 64B lines
    float* ob = out + (size_t)b * COUT * (HH * WW);
    #pragma unroll
    for (int ot = 0; ot < 8; ++ot) {
        #pragma unroll
        for (int r4 = 0; r4 < 4; ++r4) {
            const int o = (ot << 4) + (g4 << 2) + r4;
            const float bv = bias[o];
            #pragma unroll
            for (int r = 0; r < 2; ++r) {
                #pragma unroll
                for (int pt = 0; pt < 2; ++pt) {
                    const int px = x0w + (pt << 4) + l15;
                    ob[(size_t)o * (HH * WW) + (size_t)(ystart + r) * WW + px]
                        = acc[r][pt][ot][r4] + bv;
                }
            }
        }
    }
}

extern "C" void kernel_launch(void* const* d_in, const int* in_sizes, int n_in,
                              void* d_out, int out_size, void* d_ws, size_t ws_size,
                              hipStream_t stream) {
    const float* inp  = (const float*)d_in[0];
    const float* gbuf = (const float*)d_in[1];
    const float* wts  = (const float*)d_in[2];
    const float* bias = (const float*)d_in[3];

    _Float16* T  = (_Float16*)d_ws;                     // 17,305,600 B
    _Float16* bp = (_Float16*)((char*)d_ws + TSIZE);    // +147,456 B

    hipLaunchKernelGGL(prep_plus, dim3(353), dim3(256), 0, stream, wts, bp, T);
    hipLaunchKernelGGL(transpose_pass, dim3(BB * HH), dim3(256), 0, stream, inp, T);
    hipLaunchKernelGGL(depthcnn_main, dim3(512), dim3(256), 0, stream,
                       T, gbuf, bias, bp, (float*)d_out);
}

// Round 24
// 47.494 us; speedup vs baseline: 1.2714x; 1.2714x over previous
//
#include <hip/hip_runtime.h>
#include <hip/hip_bf16.h>
#include <stdint.h>

typedef _Float16 f16x8 __attribute__((ext_vector_type(8)));
typedef float    f32x4 __attribute__((ext_vector_type(4)));

#define CIN   64
#define COUT  128
#define HH    128
#define WW    128
#define BB    8

#define TROW  130                         // y' rows per batch (halo rows 0,129 zero)
#define ROWBYTES (130 * 128)              // 16640 B per (b,y') row: 130 x' * 64c * 2B
#define TSIZE ((size_t)BB * TROW * ROWBYTES)   // 17,305,600 B

#define AS1 __attribute__((address_space(1)))
#define AS3 __attribute__((address_space(3)))

// T row byte layout (f16, c-innermost, XOR-swizzled 16B slots):
//   byte(x', c) = x'*128 + (((c>>3) ^ (x'&7)) << 4) + (c&7)*2

// ---------------- pass 0: weights -> MFMA-A frag order (f16) + halo-row zeroing --
// frag[((ot*18 + s)*64 + lane)*8 + j] = W2[ot*16+(l&15)][c*9+k],
//   c = (s&1)*32 + ((l>>4)&3)*8 + j; k = s>>1
__global__ void prep_plus(const float* __restrict__ wflat, _Float16* __restrict__ bp,
                          _Float16* __restrict__ T) {
    int gid = blockIdx.x * 256 + threadIdx.x;
    if (gid < 8 * 18 * 64 * 8) {
        int j = gid & 7;
        int l = (gid >> 3) & 63;
        int s = (gid >> 9) % 18;
        int n = gid / (18 * 512);
        int o = n * 16 + (l & 15);
        int c = ((s & 1) << 5) + ((l >> 4) << 3) + j;
        int k = s >> 1;
        bp[gid] = (_Float16)wflat[o * 576 + c * 9 + k];
        return;
    }
    int h = gid - 8 * 18 * 64 * 8;
    if (h < 16 * 1040) {                  // zero halo rows y'=0,129 of each batch
        int row = h / 1040, c = h - row * 1040;
        int b = row >> 1, yp = (row & 1) * 129;
        f16x8 z = {};
        *(f16x8*)((char*)T + (size_t)(b * TROW + yp) * ROWBYTES + c * 16) = z;
    }
}

// ---------------- pass 1: input (B,C,H,W) f32 -> T[b][y'][x'][c] f16, swizzled ---
__global__ __launch_bounds__(256) void transpose_pass(const float* __restrict__ inp,
                                                      _Float16* __restrict__ T) {
    __shared__ float sT[64][129];
    const int b   = blockIdx.x >> 7;
    const int y   = blockIdx.x & 127;
    const int tid = threadIdx.x;

    const float* ib = inp + ((long)b * CIN * HH + y) * WW;
    const int xq = tid & 31, c8 = tid >> 5;
    #pragma unroll
    for (int i = 0; i < 8; ++i) {
        int c = c8 * 8 + i;
        float4 v = *(const float4*)(ib + (long)c * (HH * WW) + (xq << 2));
        *(float4*)&sT[c][xq << 2] = v;
    }
    __syncthreads();

    const int x  = tid & 127;
    const int ch = tid >> 7;
    char* rowp = (char*)T + (size_t)(b * TROW + y + 1) * ROWBYTES + (size_t)(x + 1) * 128;
    const int sw = (x + 1) & 7;
    for (int c0 = ch * 8; c0 < 64; c0 += 16) {
        f16x8 v;
        #pragma unroll
        for (int j = 0; j < 8; ++j) v[j] = (_Float16)sT[c0 + j][x];
        *(f16x8*)(rowp + (((c0 >> 3) ^ sw) << 4)) = v;
    }
    if (tid < 16) {   // zero col halos x'=0, x'=129
        char* basep = (char*)T + (size_t)(b * TROW + y + 1) * ROWBYTES
                    + ((tid >> 3) ? 129 * 128 : 0) + (tid & 7) * 16;
        f16x8 z = {};
        *(f16x8*)basep = z;
    }
}

// ---- pass 2: main — block = (b, 2-row strip), FULL 128 px x 128 o ---------------
// 256 thr = 4 waves = 4 px-quarters; EACH wave computes ALL 128 o for its 32 px
// x 2 rows. Per K-step: 4 ds_read_b128 -> 32 MFMAs (read:MFMA = 0.125). Weights
// streamed once per wave (147KB, L2-hot) via 2-deep double buffer af[2][8].
// acc[2][2][8] in AGPRs. One barrier; K-loop barrier-free, base+imm addressing.
// setprio(1) around MFMA cluster is LOAD-BEARING here (R23 A/B: removing it
// regressed 50->67us, FETCH 9.4->26MB, WRITE 65->98MB).
__global__ __launch_bounds__(256, 2) void depthcnn_main(
    const _Float16* __restrict__ T, const float* __restrict__ gbuf,
    const float* __restrict__ bias, const _Float16* __restrict__ aprep,
    float* __restrict__ out)
{
    __shared__ __align__(1024) char sIn[4 * ROWBYTES];   // 66,560 B: 4 full T rows
    __shared__ _Float16 sWf[2][9][128];                  // 4,608 B -> 71,168 total

    const int blk    = blockIdx.x;
    const int b      = blk & 7;            // XCD-pinned: batch b -> XCD b
    const int strip  = blk >> 3;           // 2-row strip (0..63)
    const int ystart = strip << 1;

    const int tid  = threadIdx.x;
    const int wave = tid >> 6;             // px quarter 0..3
    const int lane = tid & 63;
    const int l15  = lane & 15;
    const int g4   = lane >> 4;
    const int x0w  = wave << 5;            // wave's 32-px base

    // ---- stage 4 full T rows (ystart..ystart+3) via async DMA (4160 chunks)
    {
        const char* Tb = (const char*)T + ((size_t)b * TROW + ystart) * ROWBYTES;
        #pragma unroll
        for (int tt = 0; tt < 17; ++tt) {
            int t = tt * 256 + tid;
            if (t < 4 * 1040) {
                int tr = t / 1040, c = t - tr * 1040;
                __builtin_amdgcn_global_load_lds(
                    (const AS1 uint32_t*)(Tb + (size_t)tr * ROWBYTES + c * 16),
                    (AS3 uint32_t*)(sIn + tr * ROWBYTES + c * 16), 16, 0, 0);
            }
        }
    }

    // ---- weight tap-0 frags for all 8 o-tiles, issued before the barrier
    const char* ap = (const char*)aprep + lane * 16;     // + (ot*18 + s)*1024
    f16x8 af[2][8];
    #pragma unroll
    for (int ot = 0; ot < 8; ++ot)
        af[0][ot] = *(const f16x8*)(ap + (size_t)(ot * 18) * 1024);

    // ---- wf: one (row, px) item per thread — fully parallel
    {
        const int r = tid >> 7, px = tid & 127, y = ystart + r;
        const float* g = gbuf + ((size_t)b * 2 + 1) * (HH * WW);
        float dc = 2.f * (g[y * WW + px] - 0.5f);
        float e[9];
        float ssum = 0.f;
        #pragma unroll
        for (int k = 0; k < 9; ++k) {
            int yy = y + (k / 3) - 1;
            int xx = px + (k % 3) - 1;
            float dn = 0.f;
            if ((unsigned)yy < 128u && (unsigned)xx < 128u)
                dn = 2.f * (g[yy * WW + xx] - 0.5f);
            float df = dn - dc;
            float ek = __expf(-df * df);
            e[k] = ek;
            ssum += ek;
        }
        float sc = 9.f / ssum;
        #pragma unroll
        for (int k = 0; k < 9; ++k) sWf[r][k][px] = (_Float16)(e[k] * sc);
    }

    __syncthreads();   // ONE barrier: DMA stage + wf visible. K-loop barrier-free.

    // ---- precomputed swizzled LDS bases: 6 input (dx,ch) + 1 wf
    const char* binA[3][2];
    #pragma unroll
    for (int d = 0; d < 3; ++d)
        #pragma unroll
        for (int ch = 0; ch < 2; ++ch)
            binA[d][ch] = sIn + (x0w << 7) + (((l15 + d) << 7)
                        + ((((ch << 2) | g4) ^ ((l15 + d) & 7)) << 4));
    const char* bwf = (const char*)&sWf[0][0][0] + ((x0w + l15) << 1);
    // imm: (r*9+k)*256 + pt*32

    f32x4 acc[2][2][8];   // [row][pt][ot] — 128 AGPRs
    #pragma unroll
    for (int r = 0; r < 2; ++r)
        #pragma unroll
        for (int pt = 0; pt < 2; ++pt)
            #pragma unroll
            for (int ot = 0; ot < 8; ++ot)
                acc[r][pt][ot] = (f32x4){0.f, 0.f, 0.f, 0.f};

    #pragma unroll
    for (int s = 0; s < 18; ++s) {
        if (s < 17) {   // prefetch next K-step's 8 weight frags (L2-hot, 8KB/wave)
            #pragma unroll
            for (int ot = 0; ot < 8; ++ot)
                af[(s + 1) & 1][ot] = *(const f16x8*)(ap + (size_t)(ot * 18 + s + 1) * 1024);
        }
        const int tap = s >> 1;
        const int ch  = s & 1;
        const int dy  = tap / 3;
        const int dx  = tap - 3 * dy;
        #pragma unroll
        for (int r = 0; r < 2; ++r) {
            _Float16 wh[2];
            #pragma unroll
            for (int pt = 0; pt < 2; ++pt)
                wh[pt] = *(const _Float16*)(bwf + ((r * 9 + tap) * 256 + pt * 32));
            f16x8 bf[2];
            #pragma unroll
            for (int pt = 0; pt < 2; ++pt) {
                f16x8 iv = *(const f16x8*)(binA[dx][ch]
                         + ((r + dy) * ROWBYTES + (pt << 11)));
                f16x8 w8 = {wh[pt], wh[pt], wh[pt], wh[pt],
                            wh[pt], wh[pt], wh[pt], wh[pt]};
                bf[pt] = iv * w8;
            }
            __builtin_amdgcn_s_setprio(1);
            #pragma unroll
            for (int ot = 0; ot < 8; ++ot) {
                acc[r][0][ot] = __builtin_amdgcn_mfma_f32_16x16x32_f16(
                    af[s & 1][ot], bf[0], acc[r][0][ot], 0, 0, 0);
                acc[r][1][ot] = __builtin_amdgcn_mfma_f32_16x16x32_f16(
                    af[s & 1][ot], bf[1], acc[r][1][ot], 0, 0, 0);
            }
            __builtin_amdgcn_s_setprio(0);
        }
    }

    // ---- epilogue: D row = o (g4*4+r4 within tile), col = px (l15) -> 64B lines
    float* ob = out + (size_t)b * COUT * (HH * WW);
    #pragma unroll
    for (int ot = 0; ot < 8; ++ot) {
        #pragma unroll
        for (int r4 = 0; r4 < 4; ++r4) {
            const int o = (ot << 4) + (g4 << 2) + r4;
            const float bv = bias[o];
            #pragma unroll
            for (int r = 0; r < 2; ++r) {
                #pragma unroll
                for (int pt = 0; pt < 2; ++pt) {
                    const int px = x0w + (pt << 4) + l15;
                    ob[(size_t)o * (HH * WW) + (size_t)(ystart + r) * WW + px]
                        = acc[r][pt][ot][r4] + bv;
                }
            }
        }
    }
}

extern "C" void kernel_launch(void* const* d_in, const int* in_sizes, int n_in,
                              void* d_out, int out_size, void* d_ws, size_t ws_size,
                              hipStream_t stream) {
    const float* inp  = (const float*)d_in[0];
    const float* gbuf = (const float*)d_in[1];
    const float* wts  = (const float*)d_in[2];
    const float* bias = (const float*)d_in[3];

    _Float16* T  = (_Float16*)d_ws;                     // 17,305,600 B
    _Float16* bp = (_Float16*)((char*)d_ws + TSIZE);    // +147,456 B

    hipLaunchKernelGGL(prep_plus, dim3(353), dim3(256), 0, stream, wts, bp, T);
    hipLaunchKernelGGL(transpose_pass, dim3(BB * HH), dim3(256), 0, stream, inp, T);
    hipLaunchKernelGGL(depthcnn_main, dim3(512), dim3(256), 0, stream,
                       T, gbuf, bias, bp, (float*)d_out);
}